// Round 8
// baseline (1191.148 us; speedup 1.0000x reference)
//
#include <hip/hip_runtime.h>
#include <stdint.h>

// Problem dims (fixed)
// B=2, S=2048, D=1024, H=16, DH=64, tokens T=4096

typedef __attribute__((ext_vector_type(8))) short short8;
typedef __attribute__((ext_vector_type(4))) float f32x4;

__device__ __forceinline__ unsigned short f2b(float f) {
  union { float f; unsigned u; } v; v.f = f;
  unsigned u = v.u;
  return (unsigned short)((u + 0x7fffu + ((u >> 16) & 1u)) >> 16);
}

__device__ __forceinline__ float b2f(unsigned short s) {
  union { unsigned u; float f; } v;
  v.u = ((unsigned)s) << 16;
  return v.f;
}

// ---------------- cast hidden_states fp32 -> bf16 ----------------
__global__ void k_cast_hs(const float* __restrict__ x, unsigned short* __restrict__ y, int n4) {
  int i = blockIdx.x * blockDim.x + threadIdx.x;
  if (i < n4) {
    float4 v = ((const float4*)x)[i];
    ushort4 o;
    o.x = f2b(v.x); o.y = f2b(v.y); o.z = f2b(v.z); o.w = f2b(v.w);
    ((ushort4*)y)[i] = o;
  }
}

// ---------------- transpose+cast the four weight matrices ----------------
__global__ void k_transpose_cast(const float* __restrict__ Wq, const float* __restrict__ Wk,
                                 const float* __restrict__ Wv, const float* __restrict__ Wo,
                                 unsigned short* __restrict__ Tq, unsigned short* __restrict__ Tk,
                                 unsigned short* __restrict__ Tv, unsigned short* __restrict__ To) {
  __shared__ float tile[32][33];
  const float* W; unsigned short* T;
  switch (blockIdx.z) {
    case 0: W = Wq; T = Tq; break;
    case 1: W = Wk; T = Tk; break;
    case 2: W = Wv; T = Tv; break;
    default: W = Wo; T = To; break;
  }
  int n0 = blockIdx.x * 32, k0 = blockIdx.y * 32;
  int tx = threadIdx.x, ty = threadIdx.y;
#pragma unroll
  for (int j = 0; j < 4; ++j)
    tile[ty + j * 8][tx] = W[(size_t)(k0 + ty + j * 8) * 1024 + n0 + tx];
  __syncthreads();
#pragma unroll
  for (int j = 0; j < 4; ++j)
    T[(size_t)(n0 + ty + j * 8) * 1024 + k0 + tx] = f2b(tile[tx][ty + j * 8]);
}

// ---------------- m97-style 128x128 bf16 MFMA GEMM, C = A @ Bt^T ----------------
// MODE 0: out bf16 [B,H,S,DH], rows=tokens, cols=D, v=(acc+bias[col])*qscale  (Q, K)
// MODE 1: out bf16 [B,H,DH,S], rows=D (dims), cols=tokens, +bias[row]  (V transposed)
// MODE 2: out fp32 h[row*1024+col] = acc + bias[col] + resid[row*1024+col]  (out proj)
template <int MODE>
__global__ __launch_bounds__(256) void k_gemm(const unsigned short* __restrict__ A,
                                              const unsigned short* __restrict__ Bt, int Kd,
                                              const float* __restrict__ bias,
                                              const float* __restrict__ resid,
                                              void* __restrict__ outp, float qscale) {
  __shared__ __align__(16) unsigned short Asm[128 * 32];
  __shared__ __align__(16) unsigned short Bsm[128 * 32];
  const int t = threadIdx.x, w = t >> 6, l = t & 63;
  const int m0 = blockIdx.y * 128, n0 = blockIdx.x * 128;
  const int wr = w >> 1, wc = w & 1;
  const int lr = l & 15, lg = l >> 4;

  f32x4 acc[4][4];
#pragma unroll
  for (int mi = 0; mi < 4; ++mi)
#pragma unroll
    for (int ni = 0; ni < 4; ++ni) acc[mi][ni] = (f32x4){0.f, 0.f, 0.f, 0.f};

  const int kcol = (l & 3) * 8;
  for (int kt = 0; kt < Kd / 32; ++kt) {
    const int k0 = kt * 32;
#pragma unroll
    for (int i = 0; i < 2; ++i) {
      int ra = (i * 4 + w) * 16 + (l >> 2);
      const unsigned short* ga = A + (size_t)(m0 + ra) * Kd + k0 + kcol;
      __builtin_amdgcn_global_load_lds((const __attribute__((address_space(1))) void*)ga,
                                       (__attribute__((address_space(3))) void*)((char*)Asm + (i * 4 + w) * 1024),
                                       16, 0, 0);
      const unsigned short* gb = Bt + (size_t)(n0 + ra) * Kd + k0 + kcol;
      __builtin_amdgcn_global_load_lds((const __attribute__((address_space(1))) void*)gb,
                                       (__attribute__((address_space(3))) void*)((char*)Bsm + (i * 4 + w) * 1024),
                                       16, 0, 0);
    }
    __syncthreads();
    short8 af[4], bfv[4];
#pragma unroll
    for (int mi = 0; mi < 4; ++mi)
      af[mi] = *(const short8*)&Asm[(wr * 64 + mi * 16 + lr) * 32 + lg * 8];
#pragma unroll
    for (int ni = 0; ni < 4; ++ni)
      bfv[ni] = *(const short8*)&Bsm[(wc * 64 + ni * 16 + lr) * 32 + lg * 8];
#pragma unroll
    for (int mi = 0; mi < 4; ++mi)
#pragma unroll
      for (int ni = 0; ni < 4; ++ni)
        acc[mi][ni] = __builtin_amdgcn_mfma_f32_16x16x32_bf16(af[mi], bfv[ni], acc[mi][ni], 0, 0, 0);
    __syncthreads();
  }

#pragma unroll
  for (int mi = 0; mi < 4; ++mi) {
#pragma unroll
    for (int ni = 0; ni < 4; ++ni) {
#pragma unroll
      for (int r = 0; r < 4; ++r) {
        int row = m0 + wr * 64 + mi * 16 + lg * 4 + r;
        int col = n0 + wc * 64 + ni * 16 + lr;
        float v = acc[mi][ni][r];
        if constexpr (MODE == 0) {
          v = (v + bias[col]) * qscale;
          int b = row >> 11, s = row & 2047, h = col >> 6, dh = col & 63;
          ((unsigned short*)outp)[((size_t)((b * 16 + h) * 2048 + s)) * 64 + dh] = f2b(v);
        } else if constexpr (MODE == 1) {
          v += bias[row];
          int h = row >> 6, dh = row & 63, b = col >> 11, s = col & 2047;
          ((unsigned short*)outp)[((size_t)((b * 16 + h) * 64 + dh)) * 2048 + s] = f2b(v);
        } else {
          v += bias[col] + resid[(size_t)row * 1024 + col];
          ((float*)outp)[(size_t)row * 1024 + col] = v;
        }
      }
    }
  }
}

// ---------------- fused attention: scores + softmax + probs write + PV ----------------
// 1-D grid 4096 blocks, 256 threads (4 waves). XCD-swizzled block mapping.
// SWAPPED QK^T: mfma(K,Q) -> lane holds one q-row (q = lane&15), k in regs.
// P processed in 4 phases of 512 cols each: wave p stages its chunk (bf16, 16.6KB LDS),
// all waves drain 4 rows each (contiguous nontemporal fp32 stores), all waves run PV
// for their own d-slice (wave w owns d-cols [16w,16w+16)) -> no cross-wave reduce.
// Small LDS (~17KB) -> 8 blocks/CU (32 waves) for latency hiding.
// NOTE: every loop touching sc[]/pk[] MUST be fully unrolled (rule #20).
__global__ __launch_bounds__(256, 8) void k_attn(const unsigned short* __restrict__ Q,
                                                 const unsigned short* __restrict__ K,
                                                 const unsigned short* __restrict__ VT,
                                                 const float* __restrict__ mask,
                                                 float* __restrict__ probs,
                                                 unsigned short* __restrict__ ctx) {
  __shared__ float smax[4][16];
  __shared__ float ssum[4][16];
  __shared__ __align__(16) unsigned short Pb[16][520];  // one 512-col chunk, bf16

  const int t = threadIdx.x, w = t >> 6, l = t & 63;
  // XCD swizzle: i = qb*32 + jj*8 + xcd ; each XCD works 4 head-pairs (2MB L2 set)
  const int i = blockIdx.x;
  const int hp = (i & 7) * 4 + ((i >> 3) & 3);
  const int qb = i >> 5;
  const int h = hp & 15, b = hp >> 4;
  const int q0 = qb * 16;
  const int lr = l & 15, lg = l >> 4;
  const size_t head = ((size_t)(b * 16 + h)) * 2048 * 64;
  const unsigned short* Qh = Q + head + (size_t)q0 * 64;
  const unsigned short* Kh = K + head;
  const unsigned short* VTh = VT + head;

  // Q fragment as B-operand: col=lr -> q row, k = lg*8+j
  short8 aq0 = *(const short8*)(Qh + lr * 64 + lg * 8);
  short8 aq1 = *(const short8*)(Qh + lr * 64 + 32 + lg * 8);

  f32x4 sc[32];
#pragma unroll
  for (int ni = 0; ni < 32; ++ni) {
    int col = w * 512 + ni * 16 + lr;  // K row (A-operand row index)
    short8 bk0 = *(const short8*)(Kh + (size_t)col * 64 + lg * 8);
    short8 bk1 = *(const short8*)(Kh + (size_t)col * 64 + 32 + lg * 8);
    f32x4 c = (f32x4){0.f, 0.f, 0.f, 0.f};
    c = __builtin_amdgcn_mfma_f32_16x16x32_bf16(bk0, aq0, c, 0, 0, 0);  // A=K, B=Q
    c = __builtin_amdgcn_mfma_f32_16x16x32_bf16(bk1, aq1, c, 0, 0, 0);
    // lane holds S[k = w*512+ni*16+lg*4+r][q = lr]; scale already folded into Q
    f32x4 mv = *(const f32x4*)(mask + b * 2048 + w * 512 + ni * 16 + lg * 4);
    sc[ni] = c + mv;
  }

  // ---- softmax: row q=lr is lane-local ----
  float vmax = -1e30f;
#pragma unroll
  for (int ni = 0; ni < 32; ++ni)
#pragma unroll
    for (int r = 0; r < 4; ++r) vmax = fmaxf(vmax, sc[ni][r]);
  vmax = fmaxf(vmax, __shfl_xor(vmax, 16));
  vmax = fmaxf(vmax, __shfl_xor(vmax, 32));
  if (l < 16) smax[w][l] = vmax;
  __syncthreads();
  float m = fmaxf(fmaxf(smax[0][lr], smax[1][lr]), fmaxf(smax[2][lr], smax[3][lr]));

  float vsum = 0.f;
#pragma unroll
  for (int ni = 0; ni < 32; ++ni)
#pragma unroll
    for (int r = 0; r < 4; ++r) {
      float p = __expf(sc[ni][r] - m);
      sc[ni][r] = p;
      vsum += p;
    }
  vsum += __shfl_xor(vsum, 16);
  vsum += __shfl_xor(vsum, 32);
  if (l < 16) ssum[w][l] = vsum;
  __syncthreads();
  float rinv = 1.f / (ssum[0][lr] + ssum[1][lr] + ssum[2][lr] + ssum[3][lr]);

  // ---- pack normalized P to bf16 in registers (sc dies here; 64 VGPR) ----
  ushort4 pk[32];
#pragma unroll
  for (int ni = 0; ni < 32; ++ni) {
    pk[ni].x = f2b(sc[ni][0] * rinv);
    pk[ni].y = f2b(sc[ni][1] * rinv);
    pk[ni].z = f2b(sc[ni][2] * rinv);
    pk[ni].w = f2b(sc[ni][3] * rinv);
  }

  f32x4 cacc = (f32x4){0.f, 0.f, 0.f, 0.f};
  const size_t prow0 = ((size_t)((b * 16 + h) * 2048 + q0)) * 2048;

#pragma unroll
  for (int p = 0; p < 4; ++p) {
    if (w == p) {
#pragma unroll
      for (int ni = 0; ni < 32; ++ni)
        *(ushort4*)&Pb[lr][ni * 16 + lg * 4] = pk[ni];
    }
    __syncthreads();
    // drain: wave w -> rows w*4..w*4+3, cols [p*512, p*512+512), 2KB contiguous/row
#pragma unroll
    for (int rr = 0; rr < 4; ++rr) {
      int row = w * 4 + rr;
      short8 pv = *(const short8*)&Pb[row][l * 8];
      f32x4 o0, o1;
      o0[0] = b2f((unsigned short)pv[0]); o0[1] = b2f((unsigned short)pv[1]);
      o0[2] = b2f((unsigned short)pv[2]); o0[3] = b2f((unsigned short)pv[3]);
      o1[0] = b2f((unsigned short)pv[4]); o1[1] = b2f((unsigned short)pv[5]);
      o1[2] = b2f((unsigned short)pv[6]); o1[3] = b2f((unsigned short)pv[7]);
      f32x4* dst = (f32x4*)(probs + prow0 + (size_t)row * 2048 + p * 512 + l * 8);
      __builtin_nontemporal_store(o0, dst);
      __builtin_nontemporal_store(o1, dst + 1);
    }
    // PV for this k-chunk: wave w computes d-cols [w*16, w*16+16)
#pragma unroll
    for (int kc = 0; kc < 16; ++kc) {
      short8 pa = *(const short8*)&Pb[lr][kc * 32 + lg * 8];
      short8 bv = *(const short8*)(VTh + (size_t)(w * 16 + lr) * 2048 + p * 512 + kc * 32 + lg * 8);
      cacc = __builtin_amdgcn_mfma_f32_16x16x32_bf16(pa, bv, cacc, 0, 0, 0);
    }
    __syncthreads();
  }

  // ---- ctx write: wave w owns d-cols [w*16,w*16+16); C layout col=lr(d), row=lg*4+r(q) ----
#pragma unroll
  for (int r = 0; r < 4; ++r) {
    int q = lg * 4 + r;
    ctx[((size_t)(b * 2048 + q0 + q)) * 1024 + h * 64 + w * 16 + lr] = f2b(cacc[r]);
  }
}

// ---------------- LayerNorm over D=1024 per token ----------------
__global__ __launch_bounds__(256) void k_ln(const float* __restrict__ hbuf, const float* __restrict__ g,
                                            const float* __restrict__ be, float* __restrict__ out) {
  __shared__ float psum[4];
  __shared__ float psq[4];
  int tok = blockIdx.x;
  int t = threadIdx.x, w = t >> 6;
  float4 v = ((const float4*)(hbuf + (size_t)tok * 1024))[t];
  float s = v.x + v.y + v.z + v.w;
  float q = v.x * v.x + v.y * v.y + v.z * v.z + v.w * v.w;
#pragma unroll
  for (int off = 32; off >= 1; off >>= 1) {
    s += __shfl_xor(s, off);
    q += __shfl_xor(q, off);
  }
  if ((t & 63) == 0) { psum[w] = s; psq[w] = q; }
  __syncthreads();
  float S = psum[0] + psum[1] + psum[2] + psum[3];
  float Qs = psq[0] + psq[1] + psq[2] + psq[3];
  float u = S * (1.f / 1024.f);
  float var = Qs * (1.f / 1024.f) - u * u;
  float rstd = rsqrtf(var + 1e-12f);
  float4 gv = ((const float4*)g)[t];
  float4 bv = ((const float4*)be)[t];
  float4 o;
  o.x = gv.x * ((v.x - u) * rstd) + bv.x;
  o.y = gv.y * ((v.y - u) * rstd) + bv.y;
  o.z = gv.z * ((v.z - u) * rstd) + bv.z;
  o.w = gv.w * ((v.w - u) * rstd) + bv.w;
  ((float4*)(out + (size_t)tok * 1024))[t] = o;
}

extern "C" void kernel_launch(void* const* d_in, const int* in_sizes, int n_in,
                              void* d_out, int out_size, void* d_ws, size_t ws_size,
                              hipStream_t stream) {
  const float* hs   = (const float*)d_in[0];
  const float* mask = (const float*)d_in[1];
  const float* Wq   = (const float*)d_in[2];
  const float* bq   = (const float*)d_in[3];
  const float* Wk   = (const float*)d_in[4];
  const float* bk   = (const float*)d_in[5];
  const float* Wv   = (const float*)d_in[6];
  const float* bv   = (const float*)d_in[7];
  const float* Wo   = (const float*)d_in[8];
  const float* bo   = (const float*)d_in[9];
  const float* lnw  = (const float*)d_in[10];
  const float* lnb  = (const float*)d_in[11];

  float* out = (float*)d_out;
  float* probs = out + (size_t)4194304;  // B*S*D = 2*2048*1024

  char* ws = (char*)d_ws;
  const size_t MB = 1u << 20;
  unsigned short* hsb = (unsigned short*)(ws + 0 * MB);    // 8 MB
  unsigned short* TqW = (unsigned short*)(ws + 8 * MB);    // 2 MB each
  unsigned short* TkW = (unsigned short*)(ws + 10 * MB);
  unsigned short* TvW = (unsigned short*)(ws + 12 * MB);
  unsigned short* ToW = (unsigned short*)(ws + 14 * MB);
  unsigned short* Qb  = (unsigned short*)(ws + 16 * MB);   // 8 MB
  unsigned short* Kb  = (unsigned short*)(ws + 24 * MB);   // 8 MB
  unsigned short* VTb = (unsigned short*)(ws + 32 * MB);   // 8 MB
  unsigned short* ctxb = (unsigned short*)(ws + 40 * MB);  // 8 MB
  float* hbuf = (float*)(ws + 48 * MB);                    // 16 MB

  k_cast_hs<<<4096, 256, 0, stream>>>(hs, hsb, 1048576);
  k_transpose_cast<<<dim3(32, 32, 4), dim3(32, 8), 0, stream>>>(Wq, Wk, Wv, Wo, TqW, TkW, TvW, ToW);

  // Q = (hs@Wq+bq)*0.125, K = hs@Wk+bk  (rows=tokens M=4096, cols=D N=1024)
  k_gemm<0><<<dim3(8, 32), 256, 0, stream>>>(hsb, TqW, 1024, bq, nullptr, Qb, 0.125f);
  k_gemm<0><<<dim3(8, 32), 256, 0, stream>>>(hsb, TkW, 1024, bk, nullptr, Kb, 1.0f);
  // VT = (hs@Wv)^T = Wv^T @ hs^T  (rows=dims M=1024, cols=tokens N=4096)
  k_gemm<1><<<dim3(32, 8), 256, 0, stream>>>(TvW, hsb, 1024, bv, nullptr, VTb, 1.0f);

  k_attn<<<4096, 256, 0, stream>>>(Qb, Kb, VTb, mask, probs, ctxb);

  // h = ctx@Wo + bo + hs
  k_gemm<2><<<dim3(8, 32), 256, 0, stream>>>(ctxb, ToW, 1024, bo, hs, hbuf, 1.0f);
  k_ln<<<4096, 256, 0, stream>>>(hbuf, lnw, lnb, out);
}

// Round 9
// 541.842 us; speedup vs baseline: 2.1983x; 2.1983x over previous
//
#include <hip/hip_runtime.h>
#include <stdint.h>

// Problem dims (fixed)
// B=2, S=2048, D=1024, H=16, DH=64, tokens T=4096

typedef __attribute__((ext_vector_type(8))) short short8;
typedef __attribute__((ext_vector_type(4))) float f32x4;

__device__ __forceinline__ unsigned short f2b(float f) {
  union { float f; unsigned u; } v; v.f = f;
  unsigned u = v.u;
  return (unsigned short)((u + 0x7fffu + ((u >> 16) & 1u)) >> 16);
}

__device__ __forceinline__ float b2f(unsigned short s) {
  union { unsigned u; float f; } v;
  v.u = ((unsigned)s) << 16;
  return v.f;
}

// ---------------- cast hidden_states fp32 -> bf16 ----------------
__global__ void k_cast_hs(const float* __restrict__ x, unsigned short* __restrict__ y, int n4) {
  int i = blockIdx.x * blockDim.x + threadIdx.x;
  if (i < n4) {
    float4 v = ((const float4*)x)[i];
    ushort4 o;
    o.x = f2b(v.x); o.y = f2b(v.y); o.z = f2b(v.z); o.w = f2b(v.w);
    ((ushort4*)y)[i] = o;
  }
}

// ---------------- transpose+cast the four weight matrices ----------------
__global__ void k_transpose_cast(const float* __restrict__ Wq, const float* __restrict__ Wk,
                                 const float* __restrict__ Wv, const float* __restrict__ Wo,
                                 unsigned short* __restrict__ Tq, unsigned short* __restrict__ Tk,
                                 unsigned short* __restrict__ Tv, unsigned short* __restrict__ To) {
  __shared__ float tile[32][33];
  const float* W; unsigned short* T;
  switch (blockIdx.z) {
    case 0: W = Wq; T = Tq; break;
    case 1: W = Wk; T = Tk; break;
    case 2: W = Wv; T = Tv; break;
    default: W = Wo; T = To; break;
  }
  int n0 = blockIdx.x * 32, k0 = blockIdx.y * 32;
  int tx = threadIdx.x, ty = threadIdx.y;
#pragma unroll
  for (int j = 0; j < 4; ++j)
    tile[ty + j * 8][tx] = W[(size_t)(k0 + ty + j * 8) * 1024 + n0 + tx];
  __syncthreads();
#pragma unroll
  for (int j = 0; j < 4; ++j)
    T[(size_t)(n0 + ty + j * 8) * 1024 + k0 + tx] = f2b(tile[tx][ty + j * 8]);
}

// ---------------- m97-style 128x128 bf16 MFMA GEMM, C = A @ Bt^T ----------------
// MODE 0: out bf16 [B,H,S,DH], rows=tokens, cols=D, v=(acc+bias[col])*qscale  (Q, K)
// MODE 1: out bf16 [B,H,DH,S], rows=D (dims), cols=tokens, +bias[row]  (V transposed)
// MODE 2: out fp32 h[row*1024+col] = acc + bias[col] + resid[row*1024+col]  (out proj)
template <int MODE>
__global__ __launch_bounds__(256) void k_gemm(const unsigned short* __restrict__ A,
                                              const unsigned short* __restrict__ Bt, int Kd,
                                              const float* __restrict__ bias,
                                              const float* __restrict__ resid,
                                              void* __restrict__ outp, float qscale) {
  __shared__ __align__(16) unsigned short Asm[128 * 32];
  __shared__ __align__(16) unsigned short Bsm[128 * 32];
  const int t = threadIdx.x, w = t >> 6, l = t & 63;
  const int m0 = blockIdx.y * 128, n0 = blockIdx.x * 128;
  const int wr = w >> 1, wc = w & 1;
  const int lr = l & 15, lg = l >> 4;

  f32x4 acc[4][4];
#pragma unroll
  for (int mi = 0; mi < 4; ++mi)
#pragma unroll
    for (int ni = 0; ni < 4; ++ni) acc[mi][ni] = (f32x4){0.f, 0.f, 0.f, 0.f};

  const int kcol = (l & 3) * 8;
  for (int kt = 0; kt < Kd / 32; ++kt) {
    const int k0 = kt * 32;
#pragma unroll
    for (int i = 0; i < 2; ++i) {
      int ra = (i * 4 + w) * 16 + (l >> 2);
      const unsigned short* ga = A + (size_t)(m0 + ra) * Kd + k0 + kcol;
      __builtin_amdgcn_global_load_lds((const __attribute__((address_space(1))) void*)ga,
                                       (__attribute__((address_space(3))) void*)((char*)Asm + (i * 4 + w) * 1024),
                                       16, 0, 0);
      const unsigned short* gb = Bt + (size_t)(n0 + ra) * Kd + k0 + kcol;
      __builtin_amdgcn_global_load_lds((const __attribute__((address_space(1))) void*)gb,
                                       (__attribute__((address_space(3))) void*)((char*)Bsm + (i * 4 + w) * 1024),
                                       16, 0, 0);
    }
    __syncthreads();
    short8 af[4], bfv[4];
#pragma unroll
    for (int mi = 0; mi < 4; ++mi)
      af[mi] = *(const short8*)&Asm[(wr * 64 + mi * 16 + lr) * 32 + lg * 8];
#pragma unroll
    for (int ni = 0; ni < 4; ++ni)
      bfv[ni] = *(const short8*)&Bsm[(wc * 64 + ni * 16 + lr) * 32 + lg * 8];
#pragma unroll
    for (int mi = 0; mi < 4; ++mi)
#pragma unroll
      for (int ni = 0; ni < 4; ++ni)
        acc[mi][ni] = __builtin_amdgcn_mfma_f32_16x16x32_bf16(af[mi], bfv[ni], acc[mi][ni], 0, 0, 0);
    __syncthreads();
  }

#pragma unroll
  for (int mi = 0; mi < 4; ++mi) {
#pragma unroll
    for (int ni = 0; ni < 4; ++ni) {
#pragma unroll
      for (int r = 0; r < 4; ++r) {
        int row = m0 + wr * 64 + mi * 16 + lg * 4 + r;
        int col = n0 + wc * 64 + ni * 16 + lr;
        float v = acc[mi][ni][r];
        if constexpr (MODE == 0) {
          v = (v + bias[col]) * qscale;
          int b = row >> 11, s = row & 2047, h = col >> 6, dh = col & 63;
          ((unsigned short*)outp)[((size_t)((b * 16 + h) * 2048 + s)) * 64 + dh] = f2b(v);
        } else if constexpr (MODE == 1) {
          v += bias[row];
          int h = row >> 6, dh = row & 63, b = col >> 11, s = col & 2047;
          ((unsigned short*)outp)[((size_t)((b * 16 + h) * 64 + dh)) * 2048 + s] = f2b(v);
        } else {
          v += bias[col] + resid[(size_t)row * 1024 + col];
          ((float*)outp)[(size_t)row * 1024 + col] = v;
        }
      }
    }
  }
}

// ---------------- fused attention, two-pass online softmax ----------------
// 1-D grid 4096 blocks, 256 threads (4 waves), XCD-swizzled.
// SWAPPED QK^T: mfma(K,Q) -> lane holds q-row (q=lane&15), k in (lg,reg) index.
// Pass 1: each wave scans its 512 cols with online (m,s) -- NO score storage.
// Pass 2: 4 phases x 512 cols; all waves recompute 128 cols each, exp+normalize,
// stage bf16 into 16.6KB Pb, drain contiguous NT stores, d-split PV.
// Live state ~70-90 VGPR -> 6-7 waves/SIMD occupancy without spill.
__global__ __launch_bounds__(256, 4) void k_attn(const unsigned short* __restrict__ Q,
                                                 const unsigned short* __restrict__ K,
                                                 const unsigned short* __restrict__ VT,
                                                 const float* __restrict__ mask,
                                                 float* __restrict__ probs,
                                                 unsigned short* __restrict__ ctx) {
  __shared__ float smax[4][16];
  __shared__ float ssum[4][16];
  __shared__ __align__(16) unsigned short Pb[16][520];  // one 512-col chunk, bf16

  const int t = threadIdx.x, w = t >> 6, l = t & 63;
  // XCD swizzle: each XCD works a fixed set of 4 heads (2MB K+VT L2 set)
  const int i = blockIdx.x;
  const int hp = (i & 7) * 4 + ((i >> 3) & 3);
  const int qb = i >> 5;
  const int h = hp & 15, b = hp >> 4;
  const int q0 = qb * 16;
  const int lr = l & 15, lg = l >> 4;
  const size_t head = ((size_t)(b * 16 + h)) * 2048 * 64;
  const unsigned short* Qh = Q + head + (size_t)q0 * 64;
  const unsigned short* Kh = K + head;
  const unsigned short* VTh = VT + head;
  const float* maskb = mask + b * 2048;

  // Q fragment as B-operand: col=lr -> q row, k = lg*8+j
  short8 aq0 = *(const short8*)(Qh + lr * 64 + lg * 8);
  short8 aq1 = *(const short8*)(Qh + lr * 64 + 32 + lg * 8);

  // ---- pass 1: online (m,s) over this wave's 512 cols; no storage ----
  float m_run = -1e30f, s_run = 0.f;
  for (int ni = 0; ni < 32; ++ni) {
    int colbase = w * 512 + ni * 16;
    const unsigned short* kp = Kh + (size_t)(colbase + lr) * 64;
    short8 bk0 = *(const short8*)(kp + lg * 8);
    short8 bk1 = *(const short8*)(kp + 32 + lg * 8);
    f32x4 c = (f32x4){0.f, 0.f, 0.f, 0.f};
    c = __builtin_amdgcn_mfma_f32_16x16x32_bf16(bk0, aq0, c, 0, 0, 0);
    c = __builtin_amdgcn_mfma_f32_16x16x32_bf16(bk1, aq1, c, 0, 0, 0);
    f32x4 mv = *(const f32x4*)(maskb + colbase + lg * 4);
    c += mv;
    float cm = fmaxf(fmaxf(c[0], c[1]), fmaxf(c[2], c[3]));
    float mn = fmaxf(m_run, cm);
    s_run = s_run * __expf(m_run - mn) +
            __expf(c[0] - mn) + __expf(c[1] - mn) + __expf(c[2] - mn) + __expf(c[3] - mn);
    m_run = mn;
  }
  // cross-lane merge (lanes sharing q-row lr: xor 16, 32)
#pragma unroll
  for (int off = 16; off <= 32; off <<= 1) {
    float mo = __shfl_xor(m_run, off);
    float so = __shfl_xor(s_run, off);
    float mn = fmaxf(m_run, mo);
    s_run = s_run * __expf(m_run - mn) + so * __expf(mo - mn);
    m_run = mn;
  }
  if (l < 16) { smax[w][l] = m_run; ssum[w][l] = s_run; }
  __syncthreads();
  float m = fmaxf(fmaxf(smax[0][lr], smax[1][lr]), fmaxf(smax[2][lr], smax[3][lr]));
  float s_tot = ssum[0][lr] * __expf(smax[0][lr] - m) + ssum[1][lr] * __expf(smax[1][lr] - m) +
                ssum[2][lr] * __expf(smax[2][lr] - m) + ssum[3][lr] * __expf(smax[3][lr] - m);
  float rinv = 1.f / s_tot;

  // ---- pass 2: 4 phases of 512 cols; recompute, normalize, stage, drain, PV ----
  f32x4 cacc = (f32x4){0.f, 0.f, 0.f, 0.f};
  const size_t prow0 = ((size_t)((b * 16 + h) * 2048 + q0)) * 2048;

  for (int p = 0; p < 4; ++p) {
    // wave w recomputes cols [p*512 + w*128, +128)
    for (int ni = 0; ni < 8; ++ni) {
      int colbase = p * 512 + w * 128 + ni * 16;
      const unsigned short* kp = Kh + (size_t)(colbase + lr) * 64;
      short8 bk0 = *(const short8*)(kp + lg * 8);
      short8 bk1 = *(const short8*)(kp + 32 + lg * 8);
      f32x4 c = (f32x4){0.f, 0.f, 0.f, 0.f};
      c = __builtin_amdgcn_mfma_f32_16x16x32_bf16(bk0, aq0, c, 0, 0, 0);
      c = __builtin_amdgcn_mfma_f32_16x16x32_bf16(bk1, aq1, c, 0, 0, 0);
      f32x4 mv = *(const f32x4*)(maskb + colbase + lg * 4);
      c += mv;
      ushort4 pkv;
      pkv.x = f2b(__expf(c[0] - m) * rinv);
      pkv.y = f2b(__expf(c[1] - m) * rinv);
      pkv.z = f2b(__expf(c[2] - m) * rinv);
      pkv.w = f2b(__expf(c[3] - m) * rinv);
      *(ushort4*)&Pb[lr][w * 128 + ni * 16 + lg * 4] = pkv;
    }
    __syncthreads();
    // drain: wave w -> rows w*4..w*4+3, 2KB contiguous nontemporal per row
    for (int rr = 0; rr < 4; ++rr) {
      int row = w * 4 + rr;
      short8 pv = *(const short8*)&Pb[row][l * 8];
      f32x4 o0, o1;
      o0[0] = b2f((unsigned short)pv[0]); o0[1] = b2f((unsigned short)pv[1]);
      o0[2] = b2f((unsigned short)pv[2]); o0[3] = b2f((unsigned short)pv[3]);
      o1[0] = b2f((unsigned short)pv[4]); o1[1] = b2f((unsigned short)pv[5]);
      o1[2] = b2f((unsigned short)pv[6]); o1[3] = b2f((unsigned short)pv[7]);
      f32x4* dst = (f32x4*)(probs + prow0 + (size_t)row * 2048 + p * 512 + l * 8);
      __builtin_nontemporal_store(o0, dst);
      __builtin_nontemporal_store(o1, dst + 1);
    }
    // PV for this k-chunk: wave w computes d-cols [w*16, w*16+16)
    for (int kc = 0; kc < 16; ++kc) {
      short8 pa = *(const short8*)&Pb[lr][kc * 32 + lg * 8];
      short8 bv = *(const short8*)(VTh + (size_t)(w * 16 + lr) * 2048 + p * 512 + kc * 32 + lg * 8);
      cacc = __builtin_amdgcn_mfma_f32_16x16x32_bf16(pa, bv, cacc, 0, 0, 0);
    }
    __syncthreads();
  }

  // ---- ctx write: wave w owns d-cols [w*16,w*16+16); C layout col=lr(d? no: q) ----
  // cacc lane mapping: col=lr -> d-col (B-operand = VT row), row=lg*4+r -> q
#pragma unroll
  for (int r = 0; r < 4; ++r) {
    int q = lg * 4 + r;
    ctx[((size_t)(b * 2048 + q0 + q)) * 1024 + h * 64 + w * 16 + lr] = f2b(cacc[r]);
  }
}

// ---------------- LayerNorm over D=1024 per token ----------------
__global__ __launch_bounds__(256) void k_ln(const float* __restrict__ hbuf, const float* __restrict__ g,
                                            const float* __restrict__ be, float* __restrict__ out) {
  __shared__ float psum[4];
  __shared__ float psq[4];
  int tok = blockIdx.x;
  int t = threadIdx.x, w = t >> 6;
  float4 v = ((const float4*)(hbuf + (size_t)tok * 1024))[t];
  float s = v.x + v.y + v.z + v.w;
  float q = v.x * v.x + v.y * v.y + v.z * v.z + v.w * v.w;
#pragma unroll
  for (int off = 32; off >= 1; off >>= 1) {
    s += __shfl_xor(s, off);
    q += __shfl_xor(q, off);
  }
  if ((t & 63) == 0) { psum[w] = s; psq[w] = q; }
  __syncthreads();
  float S = psum[0] + psum[1] + psum[2] + psum[3];
  float Qs = psq[0] + psq[1] + psq[2] + psq[3];
  float u = S * (1.f / 1024.f);
  float var = Qs * (1.f / 1024.f) - u * u;
  float rstd = rsqrtf(var + 1e-12f);
  float4 gv = ((const float4*)g)[t];
  float4 bv = ((const float4*)be)[t];
  float4 o;
  o.x = gv.x * ((v.x - u) * rstd) + bv.x;
  o.y = gv.y * ((v.y - u) * rstd) + bv.y;
  o.z = gv.z * ((v.z - u) * rstd) + bv.z;
  o.w = gv.w * ((v.w - u) * rstd) + bv.w;
  ((float4*)(out + (size_t)tok * 1024))[t] = o;
}

extern "C" void kernel_launch(void* const* d_in, const int* in_sizes, int n_in,
                              void* d_out, int out_size, void* d_ws, size_t ws_size,
                              hipStream_t stream) {
  const float* hs   = (const float*)d_in[0];
  const float* mask = (const float*)d_in[1];
  const float* Wq   = (const float*)d_in[2];
  const float* bq   = (const float*)d_in[3];
  const float* Wk   = (const float*)d_in[4];
  const float* bk   = (const float*)d_in[5];
  const float* Wv   = (const float*)d_in[6];
  const float* bv   = (const float*)d_in[7];
  const float* Wo   = (const float*)d_in[8];
  const float* bo   = (const float*)d_in[9];
  const float* lnw  = (const float*)d_in[10];
  const float* lnb  = (const float*)d_in[11];

  float* out = (float*)d_out;
  float* probs = out + (size_t)4194304;  // B*S*D = 2*2048*1024

  char* ws = (char*)d_ws;
  const size_t MB = 1u << 20;
  unsigned short* hsb = (unsigned short*)(ws + 0 * MB);    // 8 MB
  unsigned short* TqW = (unsigned short*)(ws + 8 * MB);    // 2 MB each
  unsigned short* TkW = (unsigned short*)(ws + 10 * MB);
  unsigned short* TvW = (unsigned short*)(ws + 12 * MB);
  unsigned short* ToW = (unsigned short*)(ws + 14 * MB);
  unsigned short* Qb  = (unsigned short*)(ws + 16 * MB);   // 8 MB
  unsigned short* Kb  = (unsigned short*)(ws + 24 * MB);   // 8 MB
  unsigned short* VTb = (unsigned short*)(ws + 32 * MB);   // 8 MB
  unsigned short* ctxb = (unsigned short*)(ws + 40 * MB);  // 8 MB
  float* hbuf = (float*)(ws + 48 * MB);                    // 16 MB

  k_cast_hs<<<4096, 256, 0, stream>>>(hs, hsb, 1048576);
  k_transpose_cast<<<dim3(32, 32, 4), dim3(32, 8), 0, stream>>>(Wq, Wk, Wv, Wo, TqW, TkW, TvW, ToW);

  // Q = (hs@Wq+bq)*0.125, K = hs@Wk+bk  (rows=tokens M=4096, cols=D N=1024)
  k_gemm<0><<<dim3(8, 32), 256, 0, stream>>>(hsb, TqW, 1024, bq, nullptr, Qb, 0.125f);
  k_gemm<0><<<dim3(8, 32), 256, 0, stream>>>(hsb, TkW, 1024, bk, nullptr, Kb, 1.0f);
  // VT = (hs@Wv)^T = Wv^T @ hs^T  (rows=dims M=1024, cols=tokens N=4096)
  k_gemm<1><<<dim3(32, 8), 256, 0, stream>>>(TvW, hsb, 1024, bv, nullptr, VTb, 1.0f);

  k_attn<<<4096, 256, 0, stream>>>(Qb, Kb, VTb, mask, probs, ctxb);

  // h = ctx@Wo + bo + hs
  k_gemm<2><<<dim3(8, 32), 256, 0, stream>>>(ctxb, ToW, 1024, bo, hs, hbuf, 1.0f);
  k_ln<<<4096, 256, 0, stream>>>(hbuf, lnw, lnb, out);
}